// Round 9
// baseline (5814.892 us; speedup 1.0000x reference)
//
#include <hip/hip_runtime.h>

typedef _Float16 half2v __attribute__((ext_vector_type(2)));
typedef _Float16 half8v __attribute__((ext_vector_type(8)));
typedef float f32x4 __attribute__((ext_vector_type(4)));

#define S_LEN 2048

// barrier draining only LDS counters (cross-wave traffic is all LDS here)
#define LDS_BARRIER() asm volatile("s_waitcnt lgkmcnt(0)\n\ts_barrier" ::: "memory")

static __device__ __forceinline__ unsigned int pk16(float a, float b) {
  half2v h; h[0] = (_Float16)a; h[1] = (_Float16)b;
  return __builtin_bit_cast(unsigned int, h);
}
static __device__ __forceinline__ float uph(unsigned short u) {
  return (float)__builtin_bit_cast(_Float16, u);
}
static __device__ __forceinline__ unsigned short f16bits(float x) {
  return __builtin_bit_cast(unsigned short, (_Float16)x);
}
static __device__ __forceinline__ float rcp_f(float x) {
  return __builtin_amdgcn_rcpf(x);
}
static __device__ __forceinline__ float sigm(float x) {
  return rcp_f(1.0f + __expf(-x));
}
static __device__ __forceinline__ float tanh_fast(float x) {
  return 1.0f - 2.0f * rcp_f(__expf(2.0f * x) + 1.0f);   // safe at +/-inf
}
static __device__ __forceinline__ float sel4(f32x4 v, int b) {
  return (b == 0) ? v[0] : (b == 1) ? v[1] : (b == 2) ? v[2] : v[3];
}
static __device__ __forceinline__ half8v cvt8(const float* p) {
  f32x4 a0 = *(const f32x4*)(p);
  f32x4 a1 = *(const f32x4*)(p + 4);
  half8v v;
  v[0] = (_Float16)a0[0]; v[1] = (_Float16)a0[1];
  v[2] = (_Float16)a0[2]; v[3] = (_Float16)a0[3];
  v[4] = (_Float16)a1[0]; v[5] = (_Float16)a1[1];
  v[6] = (_Float16)a1[2]; v[7] = (_Float16)a1[3];
  return v;
}

// ---------------------------------------------------------------------------
// Kernel 1: P[m, g*256+j] = f16( x[m,:] . W{g}_x[j,:] + b{g}[j] )  (unchanged)
// ---------------------------------------------------------------------------
__global__ __launch_bounds__(256, 2) void gemm_pre(
    const float* __restrict__ x,
    const float* __restrict__ Wz, const float* __restrict__ bz,
    const float* __restrict__ Wr, const float* __restrict__ br,
    const float* __restrict__ Wc, const float* __restrict__ bc,
    const float* __restrict__ Wh, const float* __restrict__ bh,
    unsigned short* __restrict__ P)
{
  __shared__ __align__(16) char As[128 * 128];
  __shared__ __align__(16) char Bs[128 * 128];
  const int t = threadIdx.x;
  const int lane = t & 63;
  const int wid = t >> 6;
  const int wm = wid >> 1, wn = wid & 1;
  const int n0 = blockIdx.x * 128;
  const int m0 = blockIdx.y * 128;

  f32x4 acc[4][4];
  #pragma unroll
  for (int i = 0; i < 4; ++i)
    #pragma unroll
    for (int jq = 0; jq < 4; ++jq) acc[i][jq] = f32x4{0.f, 0.f, 0.f, 0.f};

  for (int kk = 0; kk < 4; ++kk) {
    __syncthreads();
    #pragma unroll
    for (int it = 0; it < 8; ++it) {
      int fl = it * 256 + t;
      int row = fl >> 4;
      int c4 = fl & 15;
      f32x4 v = *(const f32x4*)(x + (size_t)(m0 + row) * 256 + kk * 64 + c4 * 4);
      uint2 pw; pw.x = pk16(v[0], v[1]); pw.y = pk16(v[2], v[3]);
      *(uint2*)(As + row * 128 + ((c4 * 8) ^ ((row & 7) << 4))) = pw;

      int n = n0 + row;
      int g = n >> 8; int jc = n & 255;
      const float* W = (g == 0) ? Wz : (g == 1) ? Wr : (g == 2) ? Wc : Wh;
      f32x4 wv = *(const f32x4*)(W + jc * 512 + kk * 64 + c4 * 4);
      uint2 qw; qw.x = pk16(wv[0], wv[1]); qw.y = pk16(wv[2], wv[3]);
      *(uint2*)(Bs + row * 128 + ((c4 * 8) ^ ((row & 7) << 4))) = qw;
    }
    __syncthreads();
    #pragma unroll
    for (int k2 = 0; k2 < 2; ++k2) {
      const int kb = k2 * 64 + (lane >> 4) * 16;
      half8v a[4], bfr[4];
      #pragma unroll
      for (int i = 0; i < 4; ++i) {
        int ar = wm * 64 + i * 16 + (lane & 15);
        a[i] = *(const half8v*)(As + ar * 128 + (kb ^ ((ar & 7) << 4)));
        int br2 = wn * 64 + i * 16 + (lane & 15);
        bfr[i] = *(const half8v*)(Bs + br2 * 128 + (kb ^ ((br2 & 7) << 4)));
      }
      #pragma unroll
      for (int i = 0; i < 4; ++i)
        #pragma unroll
        for (int jq = 0; jq < 4; ++jq)
          acc[i][jq] = __builtin_amdgcn_mfma_f32_16x16x32_f16(a[i], bfr[jq], acc[i][jq], 0, 0, 0);
    }
  }
  #pragma unroll
  for (int jq = 0; jq < 4; ++jq) {
    int col = n0 + wn * 64 + jq * 16 + (lane & 15);
    int g = col >> 8; int jc = col & 255;
    const float* bp = (g == 0) ? bz : (g == 1) ? br : (g == 2) ? bc : bh;
    float bias = bp[jc];
    #pragma unroll
    for (int i = 0; i < 4; ++i) {
      int rowb = m0 + wm * 64 + i * 16 + (lane >> 4) * 4;
      #pragma unroll
      for (int r = 0; r < 4; ++r) {
        float vv = acc[i][jq][r] + bias;
        P[(size_t)(rowb + r) * 1024 + col] = f16bits(vv);
      }
    }
  }
}

// ---------------------------------------------------------------------------
// Kernel 2: sequential scan, 64 blocks x 256 threads (4 waves, 1 wave/SIMD,
// 512 unified regs/wave). Wave w owns rows [w*64,+64) of each gate as 4
// groups of 16; weight frags (96 x half8v = 384 regs) live in the unified
// VGPR/AGPR file (builtin MFMA -> compiler handles class + hazard nops).
// Phase A: r+z MFMAs (B = h bcast), gates; Phase C: c MFMAs (B = r*h), combine.
// ---------------------------------------------------------------------------
__global__ __launch_bounds__(256, 1) void gru_scan(
    const float* __restrict__ Wz, const float* __restrict__ Wr,
    const float* __restrict__ Wc,
    unsigned short* P, float* __restrict__ out)
{
  __shared__ __align__(16) unsigned short h_lds[256];
  __shared__ __align__(16) unsigned short rh_lds[256];

  const int t = threadIdx.x;
  const int b = blockIdx.x;
  const int w = t >> 6;
  const int l = t & 63;
  const int col = l & 15;
  const int khi = l >> 4;          // 0..3
  const int lb = l & 3;
  const bool owner = (col < 4);    // then lb == col
  const int jbase = w * 64 + khi * 4 + lb;

  // ---- A-frags: lane (khi,col) holds W[row = w*64+g*16+col][k = kc*32+khi*8+e]
  half8v wrA[4][8], wzA[4][8], wcA[4][8];
  #pragma unroll
  for (int g = 0; g < 4; ++g) {
    int row = w * 64 + g * 16 + col;
    const float* pr = Wr + row * 512 + 256 + khi * 8;
    const float* pz = Wz + row * 512 + 256 + khi * 8;
    const float* pc = Wc + row * 512 + 256 + khi * 8;
    #pragma unroll
    for (int kc = 0; kc < 8; ++kc) {
      wrA[g][kc] = cvt8(pr + kc * 32);
      wzA[g][kc] = cvt8(pz + kc * 32);
      wcA[g][kc] = cvt8(pc + kc * 32);
    }
  }

  if (t < 128) ((unsigned int*)h_lds)[t] = 0u;

  float h[4] = {0.f, 0.f, 0.f, 0.f};
  unsigned short czx[4] = {0,0,0,0}, crx[4] = {0,0,0,0}, ccx[4] = {0,0,0,0};
  if (owner) {
    const unsigned short* pb = P + b * 1024;
    #pragma unroll
    for (int g = 0; g < 4; ++g) {
      int jg = jbase + g * 16;
      czx[g] = pb[jg]; crx[g] = pb[256 + jg]; ccx[g] = pb[512 + jg];
    }
  }
  int pcur = b * 1024;
  int pnext = pcur + 65536;
  __syncthreads();

  const f32x4 z4 = f32x4{0.f, 0.f, 0.f, 0.f};

  #pragma unroll 1
  for (int s = 0; s < S_LEN; ++s) {
    unsigned short nzx[4] = {0,0,0,0}, nrx[4] = {0,0,0,0}, ncx[4] = {0,0,0,0};
    if (owner && s + 1 < S_LEN) {
      #pragma unroll
      for (int g = 0; g < 4; ++g) {
        int jg = jbase + g * 16;
        nzx[g] = P[pnext + jg]; nrx[g] = P[pnext + 256 + jg]; ncx[g] = P[pnext + 512 + jg];
      }
    }
    // ---- Phase A: r and z matvecs (B = h broadcast across the 16 cols)
    f32x4 ar[4], az[4];
    #pragma unroll
    for (int g = 0; g < 4; ++g) { ar[g] = z4; az[g] = z4; }
    #pragma unroll
    for (int kc = 0; kc < 8; ++kc) {
      half8v hB = *(const half8v*)((const char*)h_lds + kc * 64 + khi * 16);
      #pragma unroll
      for (int g = 0; g < 4; ++g) {
        ar[g] = __builtin_amdgcn_mfma_f32_16x16x32_f16(wrA[g][kc], hB, ar[g], 0, 0, 0);
        az[g] = __builtin_amdgcn_mfma_f32_16x16x32_f16(wzA[g][kc], hB, az[g], 0, 0, 0);
      }
    }
    float zg[4];
    #pragma unroll
    for (int g = 0; g < 4; ++g) {
      float rg = sigm(sel4(ar[g], lb) + uph(crx[g]));
      zg[g] = sigm(sel4(az[g], lb) + uph(czx[g]));
      if (owner) rh_lds[jbase + g * 16] = f16bits(rg * h[g]);
    }
    LDS_BARRIER();                                     // (1) rh ready
    // ---- Phase C: c matvec (B = r*h broadcast)
    f32x4 ac[4];
    #pragma unroll
    for (int g = 0; g < 4; ++g) ac[g] = z4;
    #pragma unroll
    for (int kc = 0; kc < 8; ++kc) {
      half8v rB = *(const half8v*)((const char*)rh_lds + kc * 64 + khi * 16);
      #pragma unroll
      for (int g = 0; g < 4; ++g)
        ac[g] = __builtin_amdgcn_mfma_f32_16x16x32_f16(wcA[g][kc], rB, ac[g], 0, 0, 0);
    }
    #pragma unroll
    for (int g = 0; g < 4; ++g) {
      float ht = tanh_fast(sel4(ac[g], lb) + uph(ccx[g]));
      float hn = (1.f - zg[g]) * h[g] + zg[g] * ht;
      h[g] = hn;
      if (owner) {
        unsigned short hb = f16bits(hn);
        h_lds[jbase + g * 16] = hb;
        P[pcur + jbase + g * 16] = hb;
      }
      czx[g] = nzx[g]; crx[g] = nrx[g]; ccx[g] = ncx[g];
    }
    pcur += 65536; pnext += 65536;
    LDS_BARRIER();                                     // (2) h ready
  }
  if (owner) {
    #pragma unroll
    for (int g = 0; g < 4; ++g)
      out[(size_t)33554432 + b * 256 + jbase + g * 16] = h[g];
  }
}

// ---------------------------------------------------------------------------
// Kernel 3: g-gate + highway + LayerNorm as MFMA GEMM. (unchanged)
// ---------------------------------------------------------------------------
__global__ __launch_bounds__(512, 2) void g_mfma_ln(
    const float* __restrict__ Wh,
    const float* __restrict__ gamma, const float* __restrict__ beta,
    const unsigned short* __restrict__ P,
    float* __restrict__ out)
{
  __shared__ __align__(16) char As[128 * 128];    // hprev tile f16 (swizzled)
  __shared__ __align__(16) char Bs[256 * 128];    // Wg tile f16 (swizzled)
  __shared__ float red1[128][4];
  __shared__ float red2[128][4];
  __shared__ float2 murs[128];

  const int t = threadIdx.x;
  const int lane = t & 63;
  const int wid = t >> 6;
  const int wm = wid >> 2, wn = wid & 3;          // 2 x 4 wave grid
  const unsigned m0 = blockIdx.x * 128;

  float gam4[4], bet4[4];
  #pragma unroll
  for (int jq = 0; jq < 4; ++jq) {
    int col = wn * 64 + jq * 16 + (lane & 15);
    gam4[jq] = gamma[col];
    bet4[jq] = beta[col];
  }

  f32x4 acc[4][4];
  #pragma unroll
  for (int i = 0; i < 4; ++i)
    #pragma unroll
    for (int jq = 0; jq < 4; ++jq) acc[i][jq] = f32x4{0.f, 0.f, 0.f, 0.f};

  for (int kk = 0; kk < 4; ++kk) {
    __syncthreads();
    #pragma unroll
    for (int it = 0; it < 2; ++it) {
      int g = it * 512 + t;
      int row = g >> 3;
      int c8 = g & 7;
      int msrc = (int)m0 + row - 64;
      uint4 v = uint4{0u, 0u, 0u, 0u};
      if (msrc >= 0) v = *(const uint4*)(P + (unsigned)msrc * 1024 + kk * 64 + c8 * 8);
      *(uint4*)(As + row * 128 + ((c8 * 16) ^ ((row & 7) << 4))) = v;
    }
    #pragma unroll
    for (int it = 0; it < 4; ++it) {
      int g = it * 512 + t;
      int row = g >> 3;
      int c8 = g & 7;
      const float* src = Wh + row * 512 + 256 + kk * 64 + c8 * 8;
      f32x4 v0 = *(const f32x4*)(src);
      f32x4 v1 = *(const f32x4*)(src + 4);
      uint4 pw;
      pw.x = pk16(v0[0], v0[1]); pw.y = pk16(v0[2], v0[3]);
      pw.z = pk16(v1[0], v1[1]); pw.w = pk16(v1[2], v1[3]);
      *(uint4*)(Bs + row * 128 + ((c8 * 16) ^ ((row & 7) << 4))) = pw;
    }
    __syncthreads();
    #pragma unroll
    for (int k2 = 0; k2 < 2; ++k2) {
      const int kb = k2 * 64 + (lane >> 4) * 16;
      half8v a[4], bfr[4];
      #pragma unroll
      for (int i = 0; i < 4; ++i) {
        int ar = wm * 64 + i * 16 + (lane & 15);
        a[i] = *(const half8v*)(As + ar * 128 + (kb ^ ((ar & 7) << 4)));
        int br2 = wn * 64 + i * 16 + (lane & 15);
        bfr[i] = *(const half8v*)(Bs + br2 * 128 + (kb ^ ((br2 & 7) << 4)));
      }
      #pragma unroll
      for (int i = 0; i < 4; ++i)
        #pragma unroll
        for (int jq = 0; jq < 4; ++jq)
          acc[i][jq] = __builtin_amdgcn_mfma_f32_16x16x32_f16(a[i], bfr[jq], acc[i][jq], 0, 0, 0);
    }
  }

  #pragma unroll
  for (int i = 0; i < 4; ++i) {
    #pragma unroll
    for (int r = 0; r < 4; ++r) {
      unsigned mm = m0 + wm * 64 + i * 16 + ((lane >> 4) << 2) + r;
      unsigned bse = mm << 10;
      unsigned bsp = (mm - 64) << 10;
      #pragma unroll
      for (int jq = 0; jq < 4; ++jq) {
        int col2 = wn * 64 + jq * 16 + (lane & 15);
        float gx = uph(P[bse + 768 + col2]);
        float hnew = uph(P[bse + col2]);
        float hp = (mm >= 64) ? uph(P[bsp + col2]) : 0.f;
        float g = sigm(acc[i][jq][r] + gx);
        acc[i][jq][r] = g * hnew + (1.f - g) * hp;
      }
    }
  }
  #pragma unroll
  for (int i = 0; i < 4; ++i) {
    #pragma unroll
    for (int r = 0; r < 4; ++r) {
      float s1 = acc[i][0][r] + acc[i][1][r] + acc[i][2][r] + acc[i][3][r];
      float s2 = acc[i][0][r]*acc[i][0][r] + acc[i][1][r]*acc[i][1][r]
               + acc[i][2][r]*acc[i][2][r] + acc[i][3][r]*acc[i][3][r];
      s1 += __shfl_xor(s1, 1); s2 += __shfl_xor(s2, 1);
      s1 += __shfl_xor(s1, 2); s2 += __shfl_xor(s2, 2);
      s1 += __shfl_xor(s1, 4); s2 += __shfl_xor(s2, 4);
      s1 += __shfl_xor(s1, 8); s2 += __shfl_xor(s2, 8);
      if ((lane & 15) == 0) {
        int rowl = wm * 64 + i * 16 + ((lane >> 4) << 2) + r;
        red1[rowl][wn] = s1;
        red2[rowl][wn] = s2;
      }
    }
  }
  __syncthreads();
  if (t < 128) {
    float S1 = red1[t][0] + red1[t][1] + red1[t][2] + red1[t][3];
    float S2 = red2[t][0] + red2[t][1] + red2[t][2] + red2[t][3];
    float mu = S1 * (1.0f / 256.0f);
    float var = S2 * (1.0f / 256.0f) - mu * mu;
    murs[t] = make_float2(mu, rsqrtf(var + 1e-5f));
  }
  __syncthreads();
  #pragma unroll
  for (int i = 0; i < 4; ++i) {
    #pragma unroll
    for (int r = 0; r < 4; ++r) {
      int rowl = wm * 64 + i * 16 + ((lane >> 4) << 2) + r;
      float2 mr = murs[rowl];
      unsigned mm = m0 + rowl;
      #pragma unroll
      for (int jq = 0; jq < 4; ++jq) {
        int col2 = wn * 64 + jq * 16 + (lane & 15);
        out[(size_t)mm * 256 + col2] = (acc[i][jq][r] - mr.x) * mr.y * gam4[jq] + bet4[jq];
      }
    }
  }
}

extern "C" void kernel_launch(void* const* d_in, const int* in_sizes, int n_in,
                              void* d_out, int out_size, void* d_ws, size_t ws_size,
                              hipStream_t stream) {
  const float* x  = (const float*)d_in[0];
  const float* Wz = (const float*)d_in[1];
  const float* bz = (const float*)d_in[2];
  const float* Wr = (const float*)d_in[3];
  const float* br = (const float*)d_in[4];
  const float* Wc = (const float*)d_in[5];
  const float* bc = (const float*)d_in[6];
  const float* Wh = (const float*)d_in[7];
  const float* bh = (const float*)d_in[8];
  const float* gamma = (const float*)d_in[9];
  const float* beta  = (const float*)d_in[10];
  unsigned short* P = (unsigned short*)d_ws;   // 131072 x 1024 f16 = 256 MB
  float* out = (float*)d_out;

  dim3 g1(8, 1024);
  gemm_pre<<<g1, 256, 0, stream>>>(x, Wz, bz, Wr, br, Wc, bc, Wh, bh, P);
  gru_scan<<<64, 256, 0, stream>>>(Wz, Wr, Wc, P, out);
  g_mfma_ln<<<1024, 512, 0, stream>>>(Wh, gamma, beta, P, out);
}

// Round 10
// 3338.591 us; speedup vs baseline: 1.7417x; 1.7417x over previous
//
#include <hip/hip_runtime.h>

typedef _Float16 half2v __attribute__((ext_vector_type(2)));
typedef _Float16 half8v __attribute__((ext_vector_type(8)));
typedef float f32x4 __attribute__((ext_vector_type(4)));

#define S_LEN 2048

// barrier draining only LDS counters (cross-wave traffic is all LDS here)
#define LDS_BARRIER() asm volatile("s_waitcnt lgkmcnt(0)\n\ts_barrier" ::: "memory")

static __device__ __forceinline__ unsigned int pk16(float a, float b) {
  half2v h; h[0] = (_Float16)a; h[1] = (_Float16)b;
  return __builtin_bit_cast(unsigned int, h);
}
static __device__ __forceinline__ float uph(unsigned short u) {
  return (float)__builtin_bit_cast(_Float16, u);
}
static __device__ __forceinline__ unsigned short f16bits(float x) {
  return __builtin_bit_cast(unsigned short, (_Float16)x);
}
static __device__ __forceinline__ float rcp_f(float x) {
  return __builtin_amdgcn_rcpf(x);
}
static __device__ __forceinline__ float sigm(float x) {
  return rcp_f(1.0f + __expf(-x));
}
static __device__ __forceinline__ float tanh_fast(float x) {
  return 1.0f - 2.0f * rcp_f(__expf(2.0f * x) + 1.0f);   // safe at +/-inf
}
static __device__ __forceinline__ float sel4(f32x4 v, int b) {
  return (b == 0) ? v[0] : (b == 1) ? v[1] : (b == 2) ? v[2] : v[3];
}
static __device__ __forceinline__ half8v cvt8(const float* p) {
  f32x4 a0 = *(const f32x4*)(p);
  f32x4 a1 = *(const f32x4*)(p + 4);
  half8v v;
  v[0] = (_Float16)a0[0]; v[1] = (_Float16)a0[1];
  v[2] = (_Float16)a0[2]; v[3] = (_Float16)a0[3];
  v[4] = (_Float16)a1[0]; v[5] = (_Float16)a1[1];
  v[6] = (_Float16)a1[2]; v[7] = (_Float16)a1[3];
  return v;
}
// pack 8 consecutive f32 into 8 OCP-e4m3 bytes (one i64 MFMA fp8 fragment)
static __device__ __forceinline__ long cvt8_fp8(const float* p) {
  int lo = 0, hi = 0;
  lo = __builtin_amdgcn_cvt_pk_fp8_f32(p[0], p[1], lo, false);
  lo = __builtin_amdgcn_cvt_pk_fp8_f32(p[2], p[3], lo, true);
  hi = __builtin_amdgcn_cvt_pk_fp8_f32(p[4], p[5], hi, false);
  hi = __builtin_amdgcn_cvt_pk_fp8_f32(p[6], p[7], hi, true);
  int2 v; v.x = lo; v.y = hi;
  return __builtin_bit_cast(long, v);
}

// ---------------------------------------------------------------------------
// Kernel 1: P[m, g*256+j] = f16( x[m,:] . W{g}_x[j,:] + b{g}[j] )  (unchanged)
// ---------------------------------------------------------------------------
__global__ __launch_bounds__(256, 2) void gemm_pre(
    const float* __restrict__ x,
    const float* __restrict__ Wz, const float* __restrict__ bz,
    const float* __restrict__ Wr, const float* __restrict__ br,
    const float* __restrict__ Wc, const float* __restrict__ bc,
    const float* __restrict__ Wh, const float* __restrict__ bh,
    unsigned short* __restrict__ P)
{
  __shared__ __align__(16) char As[128 * 128];
  __shared__ __align__(16) char Bs[128 * 128];
  const int t = threadIdx.x;
  const int lane = t & 63;
  const int wid = t >> 6;
  const int wm = wid >> 1, wn = wid & 1;
  const int n0 = blockIdx.x * 128;
  const int m0 = blockIdx.y * 128;

  f32x4 acc[4][4];
  #pragma unroll
  for (int i = 0; i < 4; ++i)
    #pragma unroll
    for (int jq = 0; jq < 4; ++jq) acc[i][jq] = f32x4{0.f, 0.f, 0.f, 0.f};

  for (int kk = 0; kk < 4; ++kk) {
    __syncthreads();
    #pragma unroll
    for (int it = 0; it < 8; ++it) {
      int fl = it * 256 + t;
      int row = fl >> 4;
      int c4 = fl & 15;
      f32x4 v = *(const f32x4*)(x + (size_t)(m0 + row) * 256 + kk * 64 + c4 * 4);
      uint2 pw; pw.x = pk16(v[0], v[1]); pw.y = pk16(v[2], v[3]);
      *(uint2*)(As + row * 128 + ((c4 * 8) ^ ((row & 7) << 4))) = pw;

      int n = n0 + row;
      int g = n >> 8; int jc = n & 255;
      const float* W = (g == 0) ? Wz : (g == 1) ? Wr : (g == 2) ? Wc : Wh;
      f32x4 wv = *(const f32x4*)(W + jc * 512 + kk * 64 + c4 * 4);
      uint2 qw; qw.x = pk16(wv[0], wv[1]); qw.y = pk16(wv[2], wv[3]);
      *(uint2*)(Bs + row * 128 + ((c4 * 8) ^ ((row & 7) << 4))) = qw;
    }
    __syncthreads();
    #pragma unroll
    for (int k2 = 0; k2 < 2; ++k2) {
      const int kb = k2 * 64 + (lane >> 4) * 16;
      half8v a[4], bfr[4];
      #pragma unroll
      for (int i = 0; i < 4; ++i) {
        int ar = wm * 64 + i * 16 + (lane & 15);
        a[i] = *(const half8v*)(As + ar * 128 + (kb ^ ((ar & 7) << 4)));
        int br2 = wn * 64 + i * 16 + (lane & 15);
        bfr[i] = *(const half8v*)(Bs + br2 * 128 + (kb ^ ((br2 & 7) << 4)));
      }
      #pragma unroll
      for (int i = 0; i < 4; ++i)
        #pragma unroll
        for (int jq = 0; jq < 4; ++jq)
          acc[i][jq] = __builtin_amdgcn_mfma_f32_16x16x32_f16(a[i], bfr[jq], acc[i][jq], 0, 0, 0);
    }
  }
  #pragma unroll
  for (int jq = 0; jq < 4; ++jq) {
    int col = n0 + wn * 64 + jq * 16 + (lane & 15);
    int g = col >> 8; int jc = col & 255;
    const float* bp = (g == 0) ? bz : (g == 1) ? br : (g == 2) ? bc : bh;
    float bias = bp[jc];
    #pragma unroll
    for (int i = 0; i < 4; ++i) {
      int rowb = m0 + wm * 64 + i * 16 + (lane >> 4) * 4;
      #pragma unroll
      for (int r = 0; r < 4; ++r) {
        float vv = acc[i][jq][r] + bias;
        P[(size_t)(rowb + r) * 1024 + col] = f16bits(vv);
      }
    }
  }
}

// ---------------------------------------------------------------------------
// Kernel 2: sequential scan. 64 blocks x 512 threads (8 waves, 2/SIMD).
// Wave w owns rows [w*32,+32) of z, r, c as 2 groups of 16.
//   z/r weights: fp8 e4m3 frags (i64, 2 regs each) -> 64 regs
//   c  weights:  f16 frags (half8v, 4 regs each)   -> 64 regs
// Total ~220 regs/wave -> no spill at 2 waves/SIMD.
// h published as fp8 (B for z/r); rh published as f16 (B for c).
// ---------------------------------------------------------------------------
__global__ __launch_bounds__(512, 1) void gru_scan(
    const float* __restrict__ Wz, const float* __restrict__ Wr,
    const float* __restrict__ Wc,
    unsigned short* P, float* __restrict__ out)
{
  __shared__ __align__(16) unsigned char h8_lds[256];   // h as fp8 e4m3
  __shared__ __align__(16) unsigned short rh_lds[256];  // r*h as f16

  const int t = threadIdx.x;
  const int b = blockIdx.x;
  const int w = t >> 6;
  const int l = t & 63;
  const int col = l & 15;
  const int khi = l >> 4;          // 0..3
  const int lb = l & 3;
  const bool owner = (col < 4);    // then lb == col
  const int j0 = w * 32 + khi * 4 + lb;
  const int j1 = j0 + 16;

  // ---- A-frags: lane (khi,col) holds W[row = w*32+g*16+col][k = kc*32+khi*8+e]
  long wz8[2][8], wr8[2][8];
  half8v wcA[2][8];
  #pragma unroll
  for (int g = 0; g < 2; ++g) {
    int row = w * 32 + g * 16 + col;
    const float* pz = Wz + row * 512 + 256 + khi * 8;
    const float* pr = Wr + row * 512 + 256 + khi * 8;
    const float* pc = Wc + row * 512 + 256 + khi * 8;
    #pragma unroll
    for (int kc = 0; kc < 8; ++kc) {
      wz8[g][kc] = cvt8_fp8(pz + kc * 32);
      wr8[g][kc] = cvt8_fp8(pr + kc * 32);
      wcA[g][kc] = cvt8(pc + kc * 32);
    }
  }

  if (t < 64) ((unsigned int*)h8_lds)[t] = 0u;

  float h0 = 0.f, h1 = 0.f;
  unsigned short czx0 = 0, czx1 = 0, crx0 = 0, crx1 = 0, ccx0 = 0, ccx1 = 0;
  if (owner) {
    const unsigned short* pb = P + b * 1024;
    czx0 = pb[j0]; czx1 = pb[j1];
    crx0 = pb[256 + j0]; crx1 = pb[256 + j1];
    ccx0 = pb[512 + j0]; ccx1 = pb[512 + j1];
  }
  int pcur = b * 1024;
  int pnext = pcur + 65536;
  __syncthreads();

  const f32x4 z4 = f32x4{0.f, 0.f, 0.f, 0.f};

  #pragma unroll 1
  for (int s = 0; s < S_LEN; ++s) {
    unsigned short nzx0 = 0, nzx1 = 0, nrx0 = 0, nrx1 = 0, ncx0 = 0, ncx1 = 0;
    if (owner && s + 1 < S_LEN) {
      nzx0 = P[pnext + j0]; nzx1 = P[pnext + j1];
      nrx0 = P[pnext + 256 + j0]; nrx1 = P[pnext + 256 + j1];
      ncx0 = P[pnext + 512 + j0]; ncx1 = P[pnext + 512 + j1];
    }
    // ---- Phase A: r and z matvecs in fp8 (B = h8 broadcast across cols)
    f32x4 ar0 = z4, ar1 = z4, az0 = z4, az1 = z4;
    #pragma unroll
    for (int kc = 0; kc < 8; ++kc) {
      long hB = *(const long*)(h8_lds + kc * 32 + khi * 8);
      ar0 = __builtin_amdgcn_mfma_f32_16x16x32_fp8_fp8(wr8[0][kc], hB, ar0, 0, 0, 0);
      ar1 = __builtin_amdgcn_mfma_f32_16x16x32_fp8_fp8(wr8[1][kc], hB, ar1, 0, 0, 0);
      az0 = __builtin_amdgcn_mfma_f32_16x16x32_fp8_fp8(wz8[0][kc], hB, az0, 0, 0, 0);
      az1 = __builtin_amdgcn_mfma_f32_16x16x32_fp8_fp8(wz8[1][kc], hB, az1, 0, 0, 0);
    }
    float r0 = sigm(sel4(ar0, lb) + uph(crx0));
    float r1 = sigm(sel4(ar1, lb) + uph(crx1));
    float zg0 = sigm(sel4(az0, lb) + uph(czx0));
    float zg1 = sigm(sel4(az1, lb) + uph(czx1));
    if (owner) {
      rh_lds[j0] = f16bits(r0 * h0);
      rh_lds[j1] = f16bits(r1 * h1);
    }
    LDS_BARRIER();                                     // (1) rh ready
    // ---- Phase C: c matvec in f16 (B = r*h broadcast)
    f32x4 ac0 = z4, ac1 = z4;
    #pragma unroll
    for (int kc = 0; kc < 8; ++kc) {
      half8v rB = *(const half8v*)((const char*)rh_lds + kc * 64 + khi * 16);
      ac0 = __builtin_amdgcn_mfma_f32_16x16x32_f16(wcA[0][kc], rB, ac0, 0, 0, 0);
      ac1 = __builtin_amdgcn_mfma_f32_16x16x32_f16(wcA[1][kc], rB, ac1, 0, 0, 0);
    }
    float ht0 = tanh_fast(sel4(ac0, lb) + uph(ccx0));
    float ht1 = tanh_fast(sel4(ac1, lb) + uph(ccx1));
    float hn0 = (1.f - zg0) * h0 + zg0 * ht0;
    float hn1 = (1.f - zg1) * h1 + zg1 * ht1;
    h0 = hn0; h1 = hn1;
    if (owner) {
      h8_lds[j0] = (unsigned char)(__builtin_amdgcn_cvt_pk_fp8_f32(hn0, hn0, 0, false) & 0xff);
      h8_lds[j1] = (unsigned char)(__builtin_amdgcn_cvt_pk_fp8_f32(hn1, hn1, 0, false) & 0xff);
      P[pcur + j0] = f16bits(hn0);
      P[pcur + j1] = f16bits(hn1);
    }
    czx0 = nzx0; czx1 = nzx1; crx0 = nrx0; crx1 = nrx1; ccx0 = ncx0; ccx1 = ncx1;
    pcur += 65536; pnext += 65536;
    LDS_BARRIER();                                     // (2) h ready
  }
  if (owner) {
    out[(size_t)33554432 + b * 256 + j0] = h0;
    out[(size_t)33554432 + b * 256 + j1] = h1;
  }
}

// ---------------------------------------------------------------------------
// Kernel 3: g-gate + highway + LayerNorm as MFMA GEMM. (unchanged)
// ---------------------------------------------------------------------------
__global__ __launch_bounds__(512, 2) void g_mfma_ln(
    const float* __restrict__ Wh,
    const float* __restrict__ gamma, const float* __restrict__ beta,
    const unsigned short* __restrict__ P,
    float* __restrict__ out)
{
  __shared__ __align__(16) char As[128 * 128];    // hprev tile f16 (swizzled)
  __shared__ __align__(16) char Bs[256 * 128];    // Wg tile f16 (swizzled)
  __shared__ float red1[128][4];
  __shared__ float red2[128][4];
  __shared__ float2 murs[128];

  const int t = threadIdx.x;
  const int lane = t & 63;
  const int wid = t >> 6;
  const int wm = wid >> 2, wn = wid & 3;          // 2 x 4 wave grid
  const unsigned m0 = blockIdx.x * 128;

  float gam4[4], bet4[4];
  #pragma unroll
  for (int jq = 0; jq < 4; ++jq) {
    int col = wn * 64 + jq * 16 + (lane & 15);
    gam4[jq] = gamma[col];
    bet4[jq] = beta[col];
  }

  f32x4 acc[4][4];
  #pragma unroll
  for (int i = 0; i < 4; ++i)
    #pragma unroll
    for (int jq = 0; jq < 4; ++jq) acc[i][jq] = f32x4{0.f, 0.f, 0.f, 0.f};

  for (int kk = 0; kk < 4; ++kk) {
    __syncthreads();
    #pragma unroll
    for (int it = 0; it < 2; ++it) {
      int g = it * 512 + t;
      int row = g >> 3;
      int c8 = g & 7;
      int msrc = (int)m0 + row - 64;
      uint4 v = uint4{0u, 0u, 0u, 0u};
      if (msrc >= 0) v = *(const uint4*)(P + (unsigned)msrc * 1024 + kk * 64 + c8 * 8);
      *(uint4*)(As + row * 128 + ((c8 * 16) ^ ((row & 7) << 4))) = v;
    }
    #pragma unroll
    for (int it = 0; it < 4; ++it) {
      int g = it * 512 + t;
      int row = g >> 3;
      int c8 = g & 7;
      const float* src = Wh + row * 512 + 256 + kk * 64 + c8 * 8;
      f32x4 v0 = *(const f32x4*)(src);
      f32x4 v1 = *(const f32x4*)(src + 4);
      uint4 pw;
      pw.x = pk16(v0[0], v0[1]); pw.y = pk16(v0[2], v0[3]);
      pw.z = pk16(v1[0], v1[1]); pw.w = pk16(v1[2], v1[3]);
      *(uint4*)(Bs + row * 128 + ((c8 * 16) ^ ((row & 7) << 4))) = pw;
    }
    __syncthreads();
    #pragma unroll
    for (int k2 = 0; k2 < 2; ++k2) {
      const int kb = k2 * 64 + (lane >> 4) * 16;
      half8v a[4], bfr[4];
      #pragma unroll
      for (int i = 0; i < 4; ++i) {
        int ar = wm * 64 + i * 16 + (lane & 15);
        a[i] = *(const half8v*)(As + ar * 128 + (kb ^ ((ar & 7) << 4)));
        int br2 = wn * 64 + i * 16 + (lane & 15);
        bfr[i] = *(const half8v*)(Bs + br2 * 128 + (kb ^ ((br2 & 7) << 4)));
      }
      #pragma unroll
      for (int i = 0; i < 4; ++i)
        #pragma unroll
        for (int jq = 0; jq < 4; ++jq)
          acc[i][jq] = __builtin_amdgcn_mfma_f32_16x16x32_f16(a[i], bfr[jq], acc[i][jq], 0, 0, 0);
    }
  }

  #pragma unroll
  for (int i = 0; i < 4; ++i) {
    #pragma unroll
    for (int r = 0; r < 4; ++r) {
      unsigned mm = m0 + wm * 64 + i * 16 + ((lane >> 4) << 2) + r;
      unsigned bse = mm << 10;
      unsigned bsp = (mm - 64) << 10;
      #pragma unroll
      for (int jq = 0; jq < 4; ++jq) {
        int col2 = wn * 64 + jq * 16 + (lane & 15);
        float gx = uph(P[bse + 768 + col2]);
        float hnew = uph(P[bse + col2]);
        float hp = (mm >= 64) ? uph(P[bsp + col2]) : 0.f;
        float g = sigm(acc[i][jq][r] + gx);
        acc[i][jq][r] = g * hnew + (1.f - g) * hp;
      }
    }
  }
  #pragma unroll
  for (int i = 0; i < 4; ++i) {
    #pragma unroll
    for (int r = 0; r < 4; ++r) {
      float s1 = acc[i][0][r] + acc[i][1][r] + acc[i][2][r] + acc[i][3][r];
      float s2 = acc[i][0][r]*acc[i][0][r] + acc[i][1][r]*acc[i][1][r]
               + acc[i][2][r]*acc[i][2][r] + acc[i][3][r]*acc[i][3][r];
      s1 += __shfl_xor(s1, 1); s2 += __shfl_xor(s2, 1);
      s1 += __shfl_xor(s1, 2); s2 += __shfl_xor(s2, 2);
      s1 += __shfl_xor(s1, 4); s2 += __shfl_xor(s2, 4);
      s1 += __shfl_xor(s1, 8); s2 += __shfl_xor(s2, 8);
      if ((lane & 15) == 0) {
        int rowl = wm * 64 + i * 16 + ((lane >> 4) << 2) + r;
        red1[rowl][wn] = s1;
        red2[rowl][wn] = s2;
      }
    }
  }
  __syncthreads();
  if (t < 128) {
    float S1 = red1[t][0] + red1[t][1] + red1[t][2] + red1[t][3];
    float S2 = red2[t][0] + red2[t][1] + red2[t][2] + red2[t][3];
    float mu = S1 * (1.0f / 256.0f);
    float var = S2 * (1.0f / 256.0f) - mu * mu;
    murs[t] = make_float2(mu, rsqrtf(var + 1e-5f));
  }
  __syncthreads();
  #pragma unroll
  for (int i = 0; i < 4; ++i) {
    #pragma unroll
    for (int r = 0; r < 4; ++r) {
      int rowl = wm * 64 + i * 16 + ((lane >> 4) << 2) + r;
      float2 mr = murs[rowl];
      unsigned mm = m0 + rowl;
      #pragma unroll
      for (int jq = 0; jq < 4; ++jq) {
        int col2 = wn * 64 + jq * 16 + (lane & 15);
        out[(size_t)mm * 256 + col2] = (acc[i][jq][r] - mr.x) * mr.y * gam4[jq] + bet4[jq];
      }
    }
  }
}

extern "C" void kernel_launch(void* const* d_in, const int* in_sizes, int n_in,
                              void* d_out, int out_size, void* d_ws, size_t ws_size,
                              hipStream_t stream) {
  const float* x  = (const float*)d_in[0];
  const float* Wz = (const float*)d_in[1];
  const float* bz = (const float*)d_in[2];
  const float* Wr = (const float*)d_in[3];
  const float* br = (const float*)d_in[4];
  const float* Wc = (const float*)d_in[5];
  const float* bc = (const float*)d_in[6];
  const float* Wh = (const float*)d_in[7];
  const float* bh = (const float*)d_in[8];
  const float* gamma = (const float*)d_in[9];
  const float* beta  = (const float*)d_in[10];
  unsigned short* P = (unsigned short*)d_ws;   // 131072 x 1024 f16 = 256 MB
  float* out = (float*)d_out;

  dim3 g1(8, 1024);
  gemm_pre<<<g1, 256, 0, stream>>>(x, Wz, bz, Wr, br, Wc, bc, Wh, bh, P);
  gru_scan<<<64, 512, 0, stream>>>(Wz, Wr, Wc, P, out);
  g_mfma_ln<<<1024, 512, 0, stream>>>(Wh, gamma, beta, P, out);
}

// Round 11
// 2931.269 us; speedup vs baseline: 1.9837x; 1.1390x over previous
//
#include <hip/hip_runtime.h>

typedef _Float16 half2v __attribute__((ext_vector_type(2)));
typedef _Float16 half8v __attribute__((ext_vector_type(8)));
typedef float f32x4 __attribute__((ext_vector_type(4)));

#define S_LEN 2048

// barrier draining only LDS counters (cross-wave traffic is all LDS here)
#define LDS_BARRIER() asm volatile("s_waitcnt lgkmcnt(0)\n\ts_barrier" ::: "memory")

static __device__ __forceinline__ unsigned int pk16(float a, float b) {
  half2v h; h[0] = (_Float16)a; h[1] = (_Float16)b;
  return __builtin_bit_cast(unsigned int, h);
}
static __device__ __forceinline__ float uph(unsigned short u) {
  return (float)__builtin_bit_cast(_Float16, u);
}
static __device__ __forceinline__ unsigned short f16bits(float x) {
  return __builtin_bit_cast(unsigned short, (_Float16)x);
}
static __device__ __forceinline__ float rcp_f(float x) {
  return __builtin_amdgcn_rcpf(x);
}
static __device__ __forceinline__ float sigm(float x) {
  return rcp_f(1.0f + __expf(-x));
}
static __device__ __forceinline__ float tanh_fast(float x) {
  return 1.0f - 2.0f * rcp_f(__expf(2.0f * x) + 1.0f);   // safe at +/-inf
}
static __device__ __forceinline__ float sel4(f32x4 v, int b) {
  return (b == 0) ? v[0] : (b == 1) ? v[1] : (b == 2) ? v[2] : v[3];
}
static __device__ __forceinline__ half8v cvt8(const float* p) {
  f32x4 a0 = *(const f32x4*)(p);
  f32x4 a1 = *(const f32x4*)(p + 4);
  half8v v;
  v[0] = (_Float16)a0[0]; v[1] = (_Float16)a0[1];
  v[2] = (_Float16)a0[2]; v[3] = (_Float16)a0[3];
  v[4] = (_Float16)a1[0]; v[5] = (_Float16)a1[1];
  v[6] = (_Float16)a1[2]; v[7] = (_Float16)a1[3];
  return v;
}
// pack 8 consecutive f32 into 8 OCP-e4m3 bytes (one i64 MFMA fp8 fragment)
static __device__ __forceinline__ long cvt8_fp8(const float* p) {
  int lo = 0, hi = 0;
  lo = __builtin_amdgcn_cvt_pk_fp8_f32(p[0], p[1], lo, false);
  lo = __builtin_amdgcn_cvt_pk_fp8_f32(p[2], p[3], lo, true);
  hi = __builtin_amdgcn_cvt_pk_fp8_f32(p[4], p[5], hi, false);
  hi = __builtin_amdgcn_cvt_pk_fp8_f32(p[6], p[7], hi, true);
  int2 v; v.x = lo; v.y = hi;
  return __builtin_bit_cast(long, v);
}

// ---------------------------------------------------------------------------
// Kernel 1: P[m, g*256+j] = f16( x[m,:] . W{g}_x[j,:] + b{g}[j] )  (unchanged)
// ---------------------------------------------------------------------------
__global__ __launch_bounds__(256, 2) void gemm_pre(
    const float* __restrict__ x,
    const float* __restrict__ Wz, const float* __restrict__ bz,
    const float* __restrict__ Wr, const float* __restrict__ br,
    const float* __restrict__ Wc, const float* __restrict__ bc,
    const float* __restrict__ Wh, const float* __restrict__ bh,
    unsigned short* __restrict__ P)
{
  __shared__ __align__(16) char As[128 * 128];
  __shared__ __align__(16) char Bs[128 * 128];
  const int t = threadIdx.x;
  const int lane = t & 63;
  const int wid = t >> 6;
  const int wm = wid >> 1, wn = wid & 1;
  const int n0 = blockIdx.x * 128;
  const int m0 = blockIdx.y * 128;

  f32x4 acc[4][4];
  #pragma unroll
  for (int i = 0; i < 4; ++i)
    #pragma unroll
    for (int jq = 0; jq < 4; ++jq) acc[i][jq] = f32x4{0.f, 0.f, 0.f, 0.f};

  for (int kk = 0; kk < 4; ++kk) {
    __syncthreads();
    #pragma unroll
    for (int it = 0; it < 8; ++it) {
      int fl = it * 256 + t;
      int row = fl >> 4;
      int c4 = fl & 15;
      f32x4 v = *(const f32x4*)(x + (size_t)(m0 + row) * 256 + kk * 64 + c4 * 4);
      uint2 pw; pw.x = pk16(v[0], v[1]); pw.y = pk16(v[2], v[3]);
      *(uint2*)(As + row * 128 + ((c4 * 8) ^ ((row & 7) << 4))) = pw;

      int n = n0 + row;
      int g = n >> 8; int jc = n & 255;
      const float* W = (g == 0) ? Wz : (g == 1) ? Wr : (g == 2) ? Wc : Wh;
      f32x4 wv = *(const f32x4*)(W + jc * 512 + kk * 64 + c4 * 4);
      uint2 qw; qw.x = pk16(wv[0], wv[1]); qw.y = pk16(wv[2], wv[3]);
      *(uint2*)(Bs + row * 128 + ((c4 * 8) ^ ((row & 7) << 4))) = qw;
    }
    __syncthreads();
    #pragma unroll
    for (int k2 = 0; k2 < 2; ++k2) {
      const int kb = k2 * 64 + (lane >> 4) * 16;
      half8v a[4], bfr[4];
      #pragma unroll
      for (int i = 0; i < 4; ++i) {
        int ar = wm * 64 + i * 16 + (lane & 15);
        a[i] = *(const half8v*)(As + ar * 128 + (kb ^ ((ar & 7) << 4)));
        int br2 = wn * 64 + i * 16 + (lane & 15);
        bfr[i] = *(const half8v*)(Bs + br2 * 128 + (kb ^ ((br2 & 7) << 4)));
      }
      #pragma unroll
      for (int i = 0; i < 4; ++i)
        #pragma unroll
        for (int jq = 0; jq < 4; ++jq)
          acc[i][jq] = __builtin_amdgcn_mfma_f32_16x16x32_f16(a[i], bfr[jq], acc[i][jq], 0, 0, 0);
    }
  }
  #pragma unroll
  for (int jq = 0; jq < 4; ++jq) {
    int col = n0 + wn * 64 + jq * 16 + (lane & 15);
    int g = col >> 8; int jc = col & 255;
    const float* bp = (g == 0) ? bz : (g == 1) ? br : (g == 2) ? bc : bh;
    float bias = bp[jc];
    #pragma unroll
    for (int i = 0; i < 4; ++i) {
      int rowb = m0 + wm * 64 + i * 16 + (lane >> 4) * 4;
      #pragma unroll
      for (int r = 0; r < 4; ++r) {
        float vv = acc[i][jq][r] + bias;
        P[(size_t)(rowb + r) * 1024 + col] = f16bits(vv);
      }
    }
  }
}

// ---------------------------------------------------------------------------
// Kernel 2: sequential scan. 64 blocks x 1024 threads (16 waves, 4/SIMD).
// Wave w owns rows [w*16,+16) of z, r, c (ONE MFMA group per gate):
//   z/r: fp8 frags (16+16 regs), c: f16 frags (32 regs), working ~55
//   -> ~120 regs/wave, 4 waves/SIMD interleave the serial chains.
// 24 MFMA/wave/step; h published fp8 (B for z/r), rh f16 (B for c).
// ---------------------------------------------------------------------------
__global__ __launch_bounds__(1024, 1) void gru_scan(
    const float* __restrict__ Wz, const float* __restrict__ Wr,
    const float* __restrict__ Wc,
    unsigned short* P, float* __restrict__ out)
{
  __shared__ __align__(16) unsigned char h8_lds[256];   // h as fp8 e4m3
  __shared__ __align__(16) unsigned short rh_lds[256];  // r*h as f16

  const int t = threadIdx.x;
  const int b = blockIdx.x;
  const int w = t >> 6;            // 0..15
  const int l = t & 63;
  const int col = l & 15;
  const int khi = l >> 4;          // 0..3
  const int lb = l & 3;
  const bool owner = (col < 4);    // then lb == col
  const int j0 = w * 16 + khi * 4 + lb;

  // ---- A-frags: lane (khi,col) holds W[row = w*16+col][k = kc*32+khi*8+e]
  long wz8[8], wr8[8];
  half8v wcA[8];
  {
    int row = w * 16 + col;
    const float* pz = Wz + row * 512 + 256 + khi * 8;
    const float* pr = Wr + row * 512 + 256 + khi * 8;
    const float* pc = Wc + row * 512 + 256 + khi * 8;
    #pragma unroll
    for (int kc = 0; kc < 8; ++kc) {
      wz8[kc] = cvt8_fp8(pz + kc * 32);
      wr8[kc] = cvt8_fp8(pr + kc * 32);
      wcA[kc] = cvt8(pc + kc * 32);
    }
  }

  if (t < 64) ((unsigned int*)h8_lds)[t] = 0u;

  float h0 = 0.f;
  unsigned short czx = 0, crx = 0, ccx = 0;
  if (owner) {
    const unsigned short* pb = P + b * 1024;
    czx = pb[j0]; crx = pb[256 + j0]; ccx = pb[512 + j0];
  }
  int pcur = b * 1024;
  int pnext = pcur + 65536;
  __syncthreads();

  const f32x4 z4 = f32x4{0.f, 0.f, 0.f, 0.f};

  #pragma unroll 1
  for (int s = 0; s < S_LEN; ++s) {
    unsigned short nzx = 0, nrx = 0, ncx = 0;
    if (owner && s + 1 < S_LEN) {
      nzx = P[pnext + j0];
      nrx = P[pnext + 256 + j0];
      ncx = P[pnext + 512 + j0];
    }
    // ---- Phase A: r and z matvecs in fp8 (B = h8 broadcast across cols)
    f32x4 ar = z4, az = z4;
    #pragma unroll
    for (int kc = 0; kc < 8; ++kc) {
      long hB = *(const long*)(h8_lds + kc * 32 + khi * 8);
      ar = __builtin_amdgcn_mfma_f32_16x16x32_fp8_fp8(wr8[kc], hB, ar, 0, 0, 0);
      az = __builtin_amdgcn_mfma_f32_16x16x32_fp8_fp8(wz8[kc], hB, az, 0, 0, 0);
    }
    float r0 = sigm(sel4(ar, lb) + uph(crx));
    float zg = sigm(sel4(az, lb) + uph(czx));
    if (owner) rh_lds[j0] = f16bits(r0 * h0);
    LDS_BARRIER();                                     // (1) rh ready
    // ---- Phase C: c matvec in f16 (B = r*h broadcast)
    f32x4 ac = z4;
    #pragma unroll
    for (int kc = 0; kc < 8; ++kc) {
      half8v rB = *(const half8v*)((const char*)rh_lds + kc * 64 + khi * 16);
      ac = __builtin_amdgcn_mfma_f32_16x16x32_f16(wcA[kc], rB, ac, 0, 0, 0);
    }
    float ht = tanh_fast(sel4(ac, lb) + uph(ccx));
    float hn = (1.f - zg) * h0 + zg * ht;
    h0 = hn;
    if (owner) {
      h8_lds[j0] = (unsigned char)(__builtin_amdgcn_cvt_pk_fp8_f32(hn, hn, 0, false) & 0xff);
      P[pcur + j0] = f16bits(hn);
    }
    czx = nzx; crx = nrx; ccx = ncx;
    pcur += 65536; pnext += 65536;
    LDS_BARRIER();                                     // (2) h ready
  }
  if (owner) out[(size_t)33554432 + b * 256 + j0] = h0;
}

// ---------------------------------------------------------------------------
// Kernel 3: g-gate + highway + LayerNorm as MFMA GEMM. (unchanged)
// ---------------------------------------------------------------------------
__global__ __launch_bounds__(512, 2) void g_mfma_ln(
    const float* __restrict__ Wh,
    const float* __restrict__ gamma, const float* __restrict__ beta,
    const unsigned short* __restrict__ P,
    float* __restrict__ out)
{
  __shared__ __align__(16) char As[128 * 128];    // hprev tile f16 (swizzled)
  __shared__ __align__(16) char Bs[256 * 128];    // Wg tile f16 (swizzled)
  __shared__ float red1[128][4];
  __shared__ float red2[128][4];
  __shared__ float2 murs[128];

  const int t = threadIdx.x;
  const int lane = t & 63;
  const int wid = t >> 6;
  const int wm = wid >> 2, wn = wid & 3;          // 2 x 4 wave grid
  const unsigned m0 = blockIdx.x * 128;

  float gam4[4], bet4[4];
  #pragma unroll
  for (int jq = 0; jq < 4; ++jq) {
    int col = wn * 64 + jq * 16 + (lane & 15);
    gam4[jq] = gamma[col];
    bet4[jq] = beta[col];
  }

  f32x4 acc[4][4];
  #pragma unroll
  for (int i = 0; i < 4; ++i)
    #pragma unroll
    for (int jq = 0; jq < 4; ++jq) acc[i][jq] = f32x4{0.f, 0.f, 0.f, 0.f};

  for (int kk = 0; kk < 4; ++kk) {
    __syncthreads();
    #pragma unroll
    for (int it = 0; it < 2; ++it) {
      int g = it * 512 + t;
      int row = g >> 3;
      int c8 = g & 7;
      int msrc = (int)m0 + row - 64;
      uint4 v = uint4{0u, 0u, 0u, 0u};
      if (msrc >= 0) v = *(const uint4*)(P + (unsigned)msrc * 1024 + kk * 64 + c8 * 8);
      *(uint4*)(As + row * 128 + ((c8 * 16) ^ ((row & 7) << 4))) = v;
    }
    #pragma unroll
    for (int it = 0; it < 4; ++it) {
      int g = it * 512 + t;
      int row = g >> 3;
      int c8 = g & 7;
      const float* src = Wh + row * 512 + 256 + kk * 64 + c8 * 8;
      f32x4 v0 = *(const f32x4*)(src);
      f32x4 v1 = *(const f32x4*)(src + 4);
      uint4 pw;
      pw.x = pk16(v0[0], v0[1]); pw.y = pk16(v0[2], v0[3]);
      pw.z = pk16(v1[0], v1[1]); pw.w = pk16(v1[2], v1[3]);
      *(uint4*)(Bs + row * 128 + ((c8 * 16) ^ ((row & 7) << 4))) = pw;
    }
    __syncthreads();
    #pragma unroll
    for (int k2 = 0; k2 < 2; ++k2) {
      const int kb = k2 * 64 + (lane >> 4) * 16;
      half8v a[4], bfr[4];
      #pragma unroll
      for (int i = 0; i < 4; ++i) {
        int ar = wm * 64 + i * 16 + (lane & 15);
        a[i] = *(const half8v*)(As + ar * 128 + (kb ^ ((ar & 7) << 4)));
        int br2 = wn * 64 + i * 16 + (lane & 15);
        bfr[i] = *(const half8v*)(Bs + br2 * 128 + (kb ^ ((br2 & 7) << 4)));
      }
      #pragma unroll
      for (int i = 0; i < 4; ++i)
        #pragma unroll
        for (int jq = 0; jq < 4; ++jq)
          acc[i][jq] = __builtin_amdgcn_mfma_f32_16x16x32_f16(a[i], bfr[jq], acc[i][jq], 0, 0, 0);
    }
  }

  #pragma unroll
  for (int i = 0; i < 4; ++i) {
    #pragma unroll
    for (int r = 0; r < 4; ++r) {
      unsigned mm = m0 + wm * 64 + i * 16 + ((lane >> 4) << 2) + r;
      unsigned bse = mm << 10;
      unsigned bsp = (mm - 64) << 10;
      #pragma unroll
      for (int jq = 0; jq < 4; ++jq) {
        int col2 = wn * 64 + jq * 16 + (lane & 15);
        float gx = uph(P[bse + 768 + col2]);
        float hnew = uph(P[bse + col2]);
        float hp = (mm >= 64) ? uph(P[bsp + col2]) : 0.f;
        float g = sigm(acc[i][jq][r] + gx);
        acc[i][jq][r] = g * hnew + (1.f - g) * hp;
      }
    }
  }
  #pragma unroll
  for (int i = 0; i < 4; ++i) {
    #pragma unroll
    for (int r = 0; r < 4; ++r) {
      float s1 = acc[i][0][r] + acc[i][1][r] + acc[i][2][r] + acc[i][3][r];
      float s2 = acc[i][0][r]*acc[i][0][r] + acc[i][1][r]*acc[i][1][r]
               + acc[i][2][r]*acc[i][2][r] + acc[i][3][r]*acc[i][3][r];
      s1 += __shfl_xor(s1, 1); s2 += __shfl_xor(s2, 1);
      s1 += __shfl_xor(s1, 2); s2 += __shfl_xor(s2, 2);
      s1 += __shfl_xor(s1, 4); s2 += __shfl_xor(s2, 4);
      s1 += __shfl_xor(s1, 8); s2 += __shfl_xor(s2, 8);
      if ((lane & 15) == 0) {
        int rowl = wm * 64 + i * 16 + ((lane >> 4) << 2) + r;
        red1[rowl][wn] = s1;
        red2[rowl][wn] = s2;
      }
    }
  }
  __syncthreads();
  if (t < 128) {
    float S1 = red1[t][0] + red1[t][1] + red1[t][2] + red1[t][3];
    float S2 = red2[t][0] + red2[t][1] + red2[t][2] + red2[t][3];
    float mu = S1 * (1.0f / 256.0f);
    float var = S2 * (1.0f / 256.0f) - mu * mu;
    murs[t] = make_float2(mu, rsqrtf(var + 1e-5f));
  }
  __syncthreads();
  #pragma unroll
  for (int i = 0; i < 4; ++i) {
    #pragma unroll
    for (int r = 0; r < 4; ++r) {
      int rowl = wm * 64 + i * 16 + ((lane >> 4) << 2) + r;
      float2 mr = murs[rowl];
      unsigned mm = m0 + rowl;
      #pragma unroll
      for (int jq = 0; jq < 4; ++jq) {
        int col2 = wn * 64 + jq * 16 + (lane & 15);
        out[(size_t)mm * 256 + col2] = (acc[i][jq][r] - mr.x) * mr.y * gam4[jq] + bet4[jq];
      }
    }
  }
}

extern "C" void kernel_launch(void* const* d_in, const int* in_sizes, int n_in,
                              void* d_out, int out_size, void* d_ws, size_t ws_size,
                              hipStream_t stream) {
  const float* x  = (const float*)d_in[0];
  const float* Wz = (const float*)d_in[1];
  const float* bz = (const float*)d_in[2];
  const float* Wr = (const float*)d_in[3];
  const float* br = (const float*)d_in[4];
  const float* Wc = (const float*)d_in[5];
  const float* bc = (const float*)d_in[6];
  const float* Wh = (const float*)d_in[7];
  const float* bh = (const float*)d_in[8];
  const float* gamma = (const float*)d_in[9];
  const float* beta  = (const float*)d_in[10];
  unsigned short* P = (unsigned short*)d_ws;   // 131072 x 1024 f16 = 256 MB
  float* out = (float*)d_out;

  dim3 g1(8, 1024);
  gemm_pre<<<g1, 256, 0, stream>>>(x, Wz, bz, Wr, br, Wc, bc, Wh, bh, P);
  gru_scan<<<64, 1024, 0, stream>>>(Wz, Wr, Wc, P, out);
  g_mfma_ln<<<1024, 512, 0, stream>>>(Wh, gamma, beta, P, out);
}

// Round 12
// 2434.563 us; speedup vs baseline: 2.3885x; 1.2040x over previous
//
#include <hip/hip_runtime.h>

typedef _Float16 half2v __attribute__((ext_vector_type(2)));
typedef _Float16 half8v __attribute__((ext_vector_type(8)));
typedef float f32x4 __attribute__((ext_vector_type(4)));
typedef int i32x8 __attribute__((ext_vector_type(8)));

#define S_LEN 2048

// barrier draining only LDS counters (cross-wave traffic is all LDS here)
#define LDS_BARRIER() asm volatile("s_waitcnt lgkmcnt(0)\n\ts_barrier" ::: "memory")

static __device__ __forceinline__ unsigned int pk16(float a, float b) {
  half2v h; h[0] = (_Float16)a; h[1] = (_Float16)b;
  return __builtin_bit_cast(unsigned int, h);
}
static __device__ __forceinline__ float uph(unsigned short u) {
  return (float)__builtin_bit_cast(_Float16, u);
}
static __device__ __forceinline__ unsigned short f16bits(float x) {
  return __builtin_bit_cast(unsigned short, (_Float16)x);
}
static __device__ __forceinline__ float rcp_f(float x) {
  return __builtin_amdgcn_rcpf(x);
}
static __device__ __forceinline__ float sigm(float x) {
  return rcp_f(1.0f + __expf(-x));
}
static __device__ __forceinline__ float tanh_fast(float x) {
  return 1.0f - 2.0f * rcp_f(__expf(2.0f * x) + 1.0f);   // safe at +/-inf
}
static __device__ __forceinline__ float sel4(f32x4 v, int b) {
  return (b == 0) ? v[0] : (b == 1) ? v[1] : (b == 2) ? v[2] : v[3];
}
static __device__ __forceinline__ half8v cvt8(const float* p) {
  f32x4 a0 = *(const f32x4*)(p);
  f32x4 a1 = *(const f32x4*)(p + 4);
  half8v v;
  v[0] = (_Float16)a0[0]; v[1] = (_Float16)a0[1];
  v[2] = (_Float16)a0[2]; v[3] = (_Float16)a0[3];
  v[4] = (_Float16)a1[0]; v[5] = (_Float16)a1[1];
  v[6] = (_Float16)a1[2]; v[7] = (_Float16)a1[3];
  return v;
}
// pack 32 consecutive f32 into 32 OCP-e4m3 bytes (one K=128 MFMA fragment)
static __device__ __forceinline__ i32x8 cvt32_fp8(const float* p) {
  i32x8 v;
  #pragma unroll
  for (int q = 0; q < 4; ++q) {
    int lo = 0, hi = 0;
    lo = __builtin_amdgcn_cvt_pk_fp8_f32(p[8*q+0], p[8*q+1], lo, false);
    lo = __builtin_amdgcn_cvt_pk_fp8_f32(p[8*q+2], p[8*q+3], lo, true);
    hi = __builtin_amdgcn_cvt_pk_fp8_f32(p[8*q+4], p[8*q+5], hi, false);
    hi = __builtin_amdgcn_cvt_pk_fp8_f32(p[8*q+6], p[8*q+7], hi, true);
    v[2*q] = lo; v[2*q+1] = hi;
  }
  return v;
}

// ---------------------------------------------------------------------------
// Kernel 1: P[m, g*256+j] = f16( x[m,:] . W{g}_x[j,:] + b{g}[j] )  (unchanged)
// ---------------------------------------------------------------------------
__global__ __launch_bounds__(256, 2) void gemm_pre(
    const float* __restrict__ x,
    const float* __restrict__ Wz, const float* __restrict__ bz,
    const float* __restrict__ Wr, const float* __restrict__ br,
    const float* __restrict__ Wc, const float* __restrict__ bc,
    const float* __restrict__ Wh, const float* __restrict__ bh,
    unsigned short* __restrict__ P)
{
  __shared__ __align__(16) char As[128 * 128];
  __shared__ __align__(16) char Bs[128 * 128];
  const int t = threadIdx.x;
  const int lane = t & 63;
  const int wid = t >> 6;
  const int wm = wid >> 1, wn = wid & 1;
  const int n0 = blockIdx.x * 128;
  const int m0 = blockIdx.y * 128;

  f32x4 acc[4][4];
  #pragma unroll
  for (int i = 0; i < 4; ++i)
    #pragma unroll
    for (int jq = 0; jq < 4; ++jq) acc[i][jq] = f32x4{0.f, 0.f, 0.f, 0.f};

  for (int kk = 0; kk < 4; ++kk) {
    __syncthreads();
    #pragma unroll
    for (int it = 0; it < 8; ++it) {
      int fl = it * 256 + t;
      int row = fl >> 4;
      int c4 = fl & 15;
      f32x4 v = *(const f32x4*)(x + (size_t)(m0 + row) * 256 + kk * 64 + c4 * 4);
      uint2 pw; pw.x = pk16(v[0], v[1]); pw.y = pk16(v[2], v[3]);
      *(uint2*)(As + row * 128 + ((c4 * 8) ^ ((row & 7) << 4))) = pw;

      int n = n0 + row;
      int g = n >> 8; int jc = n & 255;
      const float* W = (g == 0) ? Wz : (g == 1) ? Wr : (g == 2) ? Wc : Wh;
      f32x4 wv = *(const f32x4*)(W + jc * 512 + kk * 64 + c4 * 4);
      uint2 qw; qw.x = pk16(wv[0], wv[1]); qw.y = pk16(wv[2], wv[3]);
      *(uint2*)(Bs + row * 128 + ((c4 * 8) ^ ((row & 7) << 4))) = qw;
    }
    __syncthreads();
    #pragma unroll
    for (int k2 = 0; k2 < 2; ++k2) {
      const int kb = k2 * 64 + (lane >> 4) * 16;
      half8v a[4], bfr[4];
      #pragma unroll
      for (int i = 0; i < 4; ++i) {
        int ar = wm * 64 + i * 16 + (lane & 15);
        a[i] = *(const half8v*)(As + ar * 128 + (kb ^ ((ar & 7) << 4)));
        int br2 = wn * 64 + i * 16 + (lane & 15);
        bfr[i] = *(const half8v*)(Bs + br2 * 128 + (kb ^ ((br2 & 7) << 4)));
      }
      #pragma unroll
      for (int i = 0; i < 4; ++i)
        #pragma unroll
        for (int jq = 0; jq < 4; ++jq)
          acc[i][jq] = __builtin_amdgcn_mfma_f32_16x16x32_f16(a[i], bfr[jq], acc[i][jq], 0, 0, 0);
    }
  }
  #pragma unroll
  for (int jq = 0; jq < 4; ++jq) {
    int col = n0 + wn * 64 + jq * 16 + (lane & 15);
    int g = col >> 8; int jc = col & 255;
    const float* bp = (g == 0) ? bz : (g == 1) ? br : (g == 2) ? bc : bh;
    float bias = bp[jc];
    #pragma unroll
    for (int i = 0; i < 4; ++i) {
      int rowb = m0 + wm * 64 + i * 16 + (lane >> 4) * 4;
      #pragma unroll
      for (int r = 0; r < 4; ++r) {
        float vv = acc[i][jq][r] + bias;
        P[(size_t)(rowb + r) * 1024 + col] = f16bits(vv);
      }
    }
  }
}

// ---------------------------------------------------------------------------
// Kernel 2: sequential scan. 64 blocks x 1024 threads (16 waves, 4/SIMD).
// Wave w owns rows [w*16,+16) of z, r, c. z/r matvecs use MX-scaled fp8
// K=128 MFMA (2 per gate, unit e8m0 scales = plain e4m3 math); c stays f16.
// h published fp8 (plain layout, 32B-contig B-frags); rh f16.
// ---------------------------------------------------------------------------
__global__ __launch_bounds__(1024, 1) void gru_scan(
    const float* __restrict__ Wz, const float* __restrict__ Wr,
    const float* __restrict__ Wc,
    unsigned short* P, float* __restrict__ out)
{
  __shared__ __align__(16) unsigned char h8_lds[256];   // h as fp8 e4m3
  __shared__ __align__(16) unsigned short rh_lds[256];  // r*h as f16

  const int t = threadIdx.x;
  const int b = blockIdx.x;
  const int w = t >> 6;            // 0..15
  const int l = t & 63;
  const int col = l & 15;
  const int khi = l >> 4;          // 0..3
  const int lb = l & 3;
  const bool owner = (col < 4);    // then lb == col
  const int j0 = w * 16 + khi * 4 + lb;

  // ---- A-frags.
  // z/r (K=128 scaled): lane (khi,col) holds W[row=w*16+col][k = half*128 + khi*32 + e]
  // c   (K=32 f16):     lane (khi,col) holds W[row][k = kc*32 + khi*8 + e]
  i32x8 wzMX[2], wrMX[2];
  half8v wcA[8];
  {
    int row = w * 16 + col;
    #pragma unroll
    for (int half = 0; half < 2; ++half) {
      wzMX[half] = cvt32_fp8(Wz + row * 512 + 256 + half * 128 + khi * 32);
      wrMX[half] = cvt32_fp8(Wr + row * 512 + 256 + half * 128 + khi * 32);
    }
    const float* pc = Wc + row * 512 + 256 + khi * 8;
    #pragma unroll
    for (int kc = 0; kc < 8; ++kc) wcA[kc] = cvt8(pc + kc * 32);
  }

  if (t < 64) ((unsigned int*)h8_lds)[t] = 0u;

  float h0 = 0.f;
  unsigned short czx = 0, crx = 0, ccx = 0;
  if (owner) {
    const unsigned short* pb = P + b * 1024;
    czx = pb[j0]; crx = pb[256 + j0]; ccx = pb[512 + j0];
  }
  int pcur = b * 1024;
  int pnext = pcur + 65536;
  __syncthreads();

  const f32x4 z4 = f32x4{0.f, 0.f, 0.f, 0.f};

  #pragma unroll 1
  for (int s = 0; s < S_LEN; ++s) {
    unsigned short nzx = 0, nrx = 0, ncx = 0;
    if (owner && s + 1 < S_LEN) {
      nzx = P[pnext + j0];
      nrx = P[pnext + 256 + j0];
      ncx = P[pnext + 512 + j0];
    }
    // ---- Phase A: r and z matvecs, MX fp8 K=128 (B = h8, 32B contig / lane)
    f32x4 ar = z4, az = z4;
    {
      i32x8 hB0 = *(const i32x8*)(h8_lds + khi * 32);
      i32x8 hB1 = *(const i32x8*)(h8_lds + 128 + khi * 32);
      ar = __builtin_amdgcn_mfma_scale_f32_16x16x128_f8f6f4(
               wrMX[0], hB0, ar, 0, 0, 0, 0x7F7F7F7F, 0, 0x7F7F7F7F);
      az = __builtin_amdgcn_mfma_scale_f32_16x16x128_f8f6f4(
               wzMX[0], hB0, az, 0, 0, 0, 0x7F7F7F7F, 0, 0x7F7F7F7F);
      ar = __builtin_amdgcn_mfma_scale_f32_16x16x128_f8f6f4(
               wrMX[1], hB1, ar, 0, 0, 0, 0x7F7F7F7F, 0, 0x7F7F7F7F);
      az = __builtin_amdgcn_mfma_scale_f32_16x16x128_f8f6f4(
               wzMX[1], hB1, az, 0, 0, 0, 0x7F7F7F7F, 0, 0x7F7F7F7F);
    }
    float r0 = sigm(sel4(ar, lb) + uph(crx));
    float zg = sigm(sel4(az, lb) + uph(czx));
    if (owner) rh_lds[j0] = f16bits(r0 * h0);
    LDS_BARRIER();                                     // (1) rh ready
    // ---- Phase C: c matvec in f16 (B = r*h broadcast)
    f32x4 ac = z4;
    #pragma unroll
    for (int kc = 0; kc < 8; ++kc) {
      half8v rB = *(const half8v*)((const char*)rh_lds + kc * 64 + khi * 16);
      ac = __builtin_amdgcn_mfma_f32_16x16x32_f16(wcA[kc], rB, ac, 0, 0, 0);
    }
    float ht = tanh_fast(sel4(ac, lb) + uph(ccx));
    float hn = (1.f - zg) * h0 + zg * ht;
    h0 = hn;
    if (owner) {
      h8_lds[j0] = (unsigned char)(__builtin_amdgcn_cvt_pk_fp8_f32(hn, hn, 0, false) & 0xff);
      P[pcur + j0] = f16bits(hn);
    }
    czx = nzx; crx = nrx; ccx = ncx;
    pcur += 65536; pnext += 65536;
    LDS_BARRIER();                                     // (2) h ready
  }
  if (owner) out[(size_t)33554432 + b * 256 + j0] = h0;
}

// ---------------------------------------------------------------------------
// Kernel 3: g-gate + highway + LayerNorm as MFMA GEMM. (unchanged)
// ---------------------------------------------------------------------------
__global__ __launch_bounds__(512, 2) void g_mfma_ln(
    const float* __restrict__ Wh,
    const float* __restrict__ gamma, const float* __restrict__ beta,
    const unsigned short* __restrict__ P,
    float* __restrict__ out)
{
  __shared__ __align__(16) char As[128 * 128];    // hprev tile f16 (swizzled)
  __shared__ __align__(16) char Bs[256 * 128];    // Wg tile f16 (swizzled)
  __shared__ float red1[128][4];
  __shared__ float red2[128][4];
  __shared__ float2 murs[128];

  const int t = threadIdx.x;
  const int lane = t & 63;
  const int wid = t >> 6;
  const int wm = wid >> 2, wn = wid & 3;          // 2 x 4 wave grid
  const unsigned m0 = blockIdx.x * 128;

  float gam4[4], bet4[4];
  #pragma unroll
  for (int jq = 0; jq < 4; ++jq) {
    int col = wn * 64 + jq * 16 + (lane & 15);
    gam4[jq] = gamma[col];
    bet4[jq] = beta[col];
  }

  f32x4 acc[4][4];
  #pragma unroll
  for (int i = 0; i < 4; ++i)
    #pragma unroll
    for (int jq = 0; jq < 4; ++jq) acc[i][jq] = f32x4{0.f, 0.f, 0.f, 0.f};

  for (int kk = 0; kk < 4; ++kk) {
    __syncthreads();
    #pragma unroll
    for (int it = 0; it < 2; ++it) {
      int g = it * 512 + t;
      int row = g >> 3;
      int c8 = g & 7;
      int msrc = (int)m0 + row - 64;
      uint4 v = uint4{0u, 0u, 0u, 0u};
      if (msrc >= 0) v = *(const uint4*)(P + (unsigned)msrc * 1024 + kk * 64 + c8 * 8);
      *(uint4*)(As + row * 128 + ((c8 * 16) ^ ((row & 7) << 4))) = v;
    }
    #pragma unroll
    for (int it = 0; it < 4; ++it) {
      int g = it * 512 + t;
      int row = g >> 3;
      int c8 = g & 7;
      const float* src = Wh + row * 512 + 256 + kk * 64 + c8 * 8;
      f32x4 v0 = *(const f32x4*)(src);
      f32x4 v1 = *(const f32x4*)(src + 4);
      uint4 pw;
      pw.x = pk16(v0[0], v0[1]); pw.y = pk16(v0[2], v0[3]);
      pw.z = pk16(v1[0], v1[1]); pw.w = pk16(v1[2], v1[3]);
      *(uint4*)(Bs + row * 128 + ((c8 * 16) ^ ((row & 7) << 4))) = pw;
    }
    __syncthreads();
    #pragma unroll
    for (int k2 = 0; k2 < 2; ++k2) {
      const int kb = k2 * 64 + (lane >> 4) * 16;
      half8v a[4], bfr[4];
      #pragma unroll
      for (int i = 0; i < 4; ++i) {
        int ar = wm * 64 + i * 16 + (lane & 15);
        a[i] = *(const half8v*)(As + ar * 128 + (kb ^ ((ar & 7) << 4)));
        int br2 = wn * 64 + i * 16 + (lane & 15);
        bfr[i] = *(const half8v*)(Bs + br2 * 128 + (kb ^ ((br2 & 7) << 4)));
      }
      #pragma unroll
      for (int i = 0; i < 4; ++i)
        #pragma unroll
        for (int jq = 0; jq < 4; ++jq)
          acc[i][jq] = __builtin_amdgcn_mfma_f32_16x16x32_f16(a[i], bfr[jq], acc[i][jq], 0, 0, 0);
    }
  }

  #pragma unroll
  for (int i = 0; i < 4; ++i) {
    #pragma unroll
    for (int r = 0; r < 4; ++r) {
      unsigned mm = m0 + wm * 64 + i * 16 + ((lane >> 4) << 2) + r;
      unsigned bse = mm << 10;
      unsigned bsp = (mm - 64) << 10;
      #pragma unroll
      for (int jq = 0; jq < 4; ++jq) {
        int col2 = wn * 64 + jq * 16 + (lane & 15);
        float gx = uph(P[bse + 768 + col2]);
        float hnew = uph(P[bse + col2]);
        float hp = (mm >= 64) ? uph(P[bsp + col2]) : 0.f;
        float g = sigm(acc[i][jq][r] + gx);
        acc[i][jq][r] = g * hnew + (1.f - g) * hp;
      }
    }
  }
  #pragma unroll
  for (int i = 0; i < 4; ++i) {
    #pragma unroll
    for (int r = 0; r < 4; ++r) {
      float s1 = acc[i][0][r] + acc[i][1][r] + acc[i][2][r] + acc[i][3][r];
      float s2 = acc[i][0][r]*acc[i][0][r] + acc[i][1][r]*acc[i][1][r]
               + acc[i][2][r]*acc[i][2][r] + acc[i][3][r]*acc[i][3][r];
      s1 += __shfl_xor(s1, 1); s2 += __shfl_xor(s2, 1);
      s1 += __shfl_xor(s1, 2); s2 += __shfl_xor(s2, 2);
      s1 += __shfl_xor(s1, 4); s2 += __shfl_xor(s2, 4);
      s1 += __shfl_xor(s1, 8); s2 += __shfl_xor(s2, 8);
      if ((lane & 15) == 0) {
        int rowl = wm * 64 + i * 16 + ((lane >> 4) << 2) + r;
        red1[rowl][wn] = s1;
        red2[rowl][wn] = s2;
      }
    }
  }
  __syncthreads();
  if (t < 128) {
    float S1 = red1[t][0] + red1[t][1] + red1[t][2] + red1[t][3];
    float S2 = red2[t][0] + red2[t][1] + red2[t][2] + red2[t][3];
    float mu = S1 * (1.0f / 256.0f);
    float var = S2 * (1.0f / 256.0f) - mu * mu;
    murs[t] = make_float2(mu, rsqrtf(var + 1e-5f));
  }
  __syncthreads();
  #pragma unroll
  for (int i = 0; i < 4; ++i) {
    #pragma unroll
    for (int r = 0; r < 4; ++r) {
      int rowl = wm * 64 + i * 16 + ((lane >> 4) << 2) + r;
      float2 mr = murs[rowl];
      unsigned mm = m0 + rowl;
      #pragma unroll
      for (int jq = 0; jq < 4; ++jq) {
        int col2 = wn * 64 + jq * 16 + (lane & 15);
        out[(size_t)mm * 256 + col2] = (acc[i][jq][r] - mr.x) * mr.y * gam4[jq] + bet4[jq];
      }
    }
  }
}

extern "C" void kernel_launch(void* const* d_in, const int* in_sizes, int n_in,
                              void* d_out, int out_size, void* d_ws, size_t ws_size,
                              hipStream_t stream) {
  const float* x  = (const float*)d_in[0];
  const float* Wz = (const float*)d_in[1];
  const float* bz = (const float*)d_in[2];
  const float* Wr = (const float*)d_in[3];
  const float* br = (const float*)d_in[4];
  const float* Wc = (const float*)d_in[5];
  const float* bc = (const float*)d_in[6];
  const float* Wh = (const float*)d_in[7];
  const float* bh = (const float*)d_in[8];
  const float* gamma = (const float*)d_in[9];
  const float* beta  = (const float*)d_in[10];
  unsigned short* P = (unsigned short*)d_ws;   // 131072 x 1024 f16 = 256 MB
  float* out = (float*)d_out;

  dim3 g1(8, 1024);
  gemm_pre<<<g1, 256, 0, stream>>>(x, Wz, bz, Wr, br, Wc, bc, Wh, bh, P);
  gru_scan<<<64, 1024, 0, stream>>>(Wz, Wr, Wc, P, out);
  g_mfma_ln<<<1024, 512, 0, stream>>>(Wh, gamma, beta, P, out);
}

// Round 13
// 2268.881 us; speedup vs baseline: 2.5629x; 1.0730x over previous
//
#include <hip/hip_runtime.h>

typedef _Float16 half2v __attribute__((ext_vector_type(2)));
typedef _Float16 half8v __attribute__((ext_vector_type(8)));
typedef float f32x4 __attribute__((ext_vector_type(4)));
typedef int i32x8 __attribute__((ext_vector_type(8)));

#define S_LEN 2048

// barrier draining only LDS counters (cross-wave traffic is all LDS here)
#define LDS_BARRIER() asm volatile("s_waitcnt lgkmcnt(0)\n\ts_barrier" ::: "memory")

static __device__ __forceinline__ unsigned int pk16(float a, float b) {
  half2v h; h[0] = (_Float16)a; h[1] = (_Float16)b;
  return __builtin_bit_cast(unsigned int, h);
}
static __device__ __forceinline__ float uph(unsigned short u) {
  return (float)__builtin_bit_cast(_Float16, u);
}
static __device__ __forceinline__ unsigned short f16bits(float x) {
  return __builtin_bit_cast(unsigned short, (_Float16)x);
}
static __device__ __forceinline__ float rcp_f(float x) {
  return __builtin_amdgcn_rcpf(x);
}
static __device__ __forceinline__ float sigm(float x) {
  return rcp_f(1.0f + __expf(-x));
}
static __device__ __forceinline__ float tanh_fast(float x) {
  return 1.0f - 2.0f * rcp_f(__expf(2.0f * x) + 1.0f);   // safe at +/-inf
}
static __device__ __forceinline__ float sel4(f32x4 v, int b) {
  return (b == 0) ? v[0] : (b == 1) ? v[1] : (b == 2) ? v[2] : v[3];
}
static __device__ __forceinline__ half8v cvt8(const float* p) {
  f32x4 a0 = *(const f32x4*)(p);
  f32x4 a1 = *(const f32x4*)(p + 4);
  half8v v;
  v[0] = (_Float16)a0[0]; v[1] = (_Float16)a0[1];
  v[2] = (_Float16)a0[2]; v[3] = (_Float16)a0[3];
  v[4] = (_Float16)a1[0]; v[5] = (_Float16)a1[1];
  v[6] = (_Float16)a1[2]; v[7] = (_Float16)a1[3];
  return v;
}
// pack 32 consecutive f32 into 32 OCP-e4m3 bytes (one K=128 MFMA fragment)
static __device__ __forceinline__ i32x8 cvt32_fp8(const float* p) {
  i32x8 v;
  #pragma unroll
  for (int q = 0; q < 4; ++q) {
    int lo = 0, hi = 0;
    lo = __builtin_amdgcn_cvt_pk_fp8_f32(p[8*q+0], p[8*q+1], lo, false);
    lo = __builtin_amdgcn_cvt_pk_fp8_f32(p[8*q+2], p[8*q+3], lo, true);
    hi = __builtin_amdgcn_cvt_pk_fp8_f32(p[8*q+4], p[8*q+5], hi, false);
    hi = __builtin_amdgcn_cvt_pk_fp8_f32(p[8*q+6], p[8*q+7], hi, true);
    v[2*q] = lo; v[2*q+1] = hi;
  }
  return v;
}

// ---------------------------------------------------------------------------
// Kernel 1: P[m, g*256+j] = f16( x[m,:] . W{g}_x[j,:] + b{g}[j] )  (unchanged)
// ---------------------------------------------------------------------------
__global__ __launch_bounds__(256, 2) void gemm_pre(
    const float* __restrict__ x,
    const float* __restrict__ Wz, const float* __restrict__ bz,
    const float* __restrict__ Wr, const float* __restrict__ br,
    const float* __restrict__ Wc, const float* __restrict__ bc,
    const float* __restrict__ Wh, const float* __restrict__ bh,
    unsigned short* __restrict__ P)
{
  __shared__ __align__(16) char As[128 * 128];
  __shared__ __align__(16) char Bs[128 * 128];
  const int t = threadIdx.x;
  const int lane = t & 63;
  const int wid = t >> 6;
  const int wm = wid >> 1, wn = wid & 1;
  const int n0 = blockIdx.x * 128;
  const int m0 = blockIdx.y * 128;

  f32x4 acc[4][4];
  #pragma unroll
  for (int i = 0; i < 4; ++i)
    #pragma unroll
    for (int jq = 0; jq < 4; ++jq) acc[i][jq] = f32x4{0.f, 0.f, 0.f, 0.f};

  for (int kk = 0; kk < 4; ++kk) {
    __syncthreads();
    #pragma unroll
    for (int it = 0; it < 8; ++it) {
      int fl = it * 256 + t;
      int row = fl >> 4;
      int c4 = fl & 15;
      f32x4 v = *(const f32x4*)(x + (size_t)(m0 + row) * 256 + kk * 64 + c4 * 4);
      uint2 pw; pw.x = pk16(v[0], v[1]); pw.y = pk16(v[2], v[3]);
      *(uint2*)(As + row * 128 + ((c4 * 8) ^ ((row & 7) << 4))) = pw;

      int n = n0 + row;
      int g = n >> 8; int jc = n & 255;
      const float* W = (g == 0) ? Wz : (g == 1) ? Wr : (g == 2) ? Wc : Wh;
      f32x4 wv = *(const f32x4*)(W + jc * 512 + kk * 64 + c4 * 4);
      uint2 qw; qw.x = pk16(wv[0], wv[1]); qw.y = pk16(wv[2], wv[3]);
      *(uint2*)(Bs + row * 128 + ((c4 * 8) ^ ((row & 7) << 4))) = qw;
    }
    __syncthreads();
    #pragma unroll
    for (int k2 = 0; k2 < 2; ++k2) {
      const int kb = k2 * 64 + (lane >> 4) * 16;
      half8v a[4], bfr[4];
      #pragma unroll
      for (int i = 0; i < 4; ++i) {
        int ar = wm * 64 + i * 16 + (lane & 15);
        a[i] = *(const half8v*)(As + ar * 128 + (kb ^ ((ar & 7) << 4)));
        int br2 = wn * 64 + i * 16 + (lane & 15);
        bfr[i] = *(const half8v*)(Bs + br2 * 128 + (kb ^ ((br2 & 7) << 4)));
      }
      #pragma unroll
      for (int i = 0; i < 4; ++i)
        #pragma unroll
        for (int jq = 0; jq < 4; ++jq)
          acc[i][jq] = __builtin_amdgcn_mfma_f32_16x16x32_f16(a[i], bfr[jq], acc[i][jq], 0, 0, 0);
    }
  }
  #pragma unroll
  for (int jq = 0; jq < 4; ++jq) {
    int col = n0 + wn * 64 + jq * 16 + (lane & 15);
    int g = col >> 8; int jc = col & 255;
    const float* bp = (g == 0) ? bz : (g == 1) ? br : (g == 2) ? bc : bh;
    float bias = bp[jc];
    #pragma unroll
    for (int i = 0; i < 4; ++i) {
      int rowb = m0 + wm * 64 + i * 16 + (lane >> 4) * 4;
      #pragma unroll
      for (int r = 0; r < 4; ++r) {
        float vv = acc[i][jq][r] + bias;
        P[(size_t)(rowb + r) * 1024 + col] = f16bits(vv);
      }
    }
  }
}

// ---------------------------------------------------------------------------
// Kernel 2: sequential scan. 64 blocks x 1024 threads (16 waves, 4/SIMD).
// Wave w owns rows [w*16,+16) of z, r, c. ALL three matvecs use MX-scaled
// fp8 K=128 MFMA (unit e8m0 scales = plain e4m3 math), 6 MFMA/wave/step.
// h and rh both published as fp8; B-frags 32B-contiguous per lane.
// ---------------------------------------------------------------------------
__global__ __launch_bounds__(1024, 1) void gru_scan(
    const float* __restrict__ Wz, const float* __restrict__ Wr,
    const float* __restrict__ Wc,
    unsigned short* P, float* __restrict__ out)
{
  __shared__ __align__(16) unsigned char h8_lds[256];   // h as fp8 e4m3
  __shared__ __align__(16) unsigned char rh8_lds[256];  // r*h as fp8 e4m3

  const int t = threadIdx.x;
  const int b = blockIdx.x;
  const int w = t >> 6;            // 0..15
  const int l = t & 63;
  const int col = l & 15;
  const int khi = l >> 4;          // 0..3
  const int lb = l & 3;
  const bool owner = (col < 4);    // then lb == col
  const int j0 = w * 16 + khi * 4 + lb;

  // ---- A-frags (K=128 scaled): lane (khi,col) holds
  //      W[row=w*16+col][k = half*128 + khi*32 + e], e=0..31
  i32x8 wzMX[2], wrMX[2], wcMX[2];
  {
    int row = w * 16 + col;
    #pragma unroll
    for (int half = 0; half < 2; ++half) {
      wzMX[half] = cvt32_fp8(Wz + row * 512 + 256 + half * 128 + khi * 32);
      wrMX[half] = cvt32_fp8(Wr + row * 512 + 256 + half * 128 + khi * 32);
      wcMX[half] = cvt32_fp8(Wc + row * 512 + 256 + half * 128 + khi * 32);
    }
  }

  if (t < 64) ((unsigned int*)h8_lds)[t] = 0u;

  float h0 = 0.f;
  unsigned short czx = 0, crx = 0, ccx = 0;
  if (owner) {
    const unsigned short* pb = P + b * 1024;
    czx = pb[j0]; crx = pb[256 + j0]; ccx = pb[512 + j0];
  }
  int pcur = b * 1024;
  int pnext = pcur + 65536;
  __syncthreads();

  const f32x4 z4 = f32x4{0.f, 0.f, 0.f, 0.f};

  #pragma unroll 1
  for (int s = 0; s < S_LEN; ++s) {
    unsigned short nzx = 0, nrx = 0, ncx = 0;
    if (owner && s + 1 < S_LEN) {
      nzx = P[pnext + j0];
      nrx = P[pnext + 256 + j0];
      ncx = P[pnext + 512 + j0];
    }
    // ---- Phase A: r and z matvecs, MX fp8 K=128 (B = h8, 32B contig / lane)
    f32x4 ar = z4, az = z4;
    {
      i32x8 hB0 = *(const i32x8*)(h8_lds + khi * 32);
      i32x8 hB1 = *(const i32x8*)(h8_lds + 128 + khi * 32);
      ar = __builtin_amdgcn_mfma_scale_f32_16x16x128_f8f6f4(
               wrMX[0], hB0, ar, 0, 0, 0, 0x7F7F7F7F, 0, 0x7F7F7F7F);
      az = __builtin_amdgcn_mfma_scale_f32_16x16x128_f8f6f4(
               wzMX[0], hB0, az, 0, 0, 0, 0x7F7F7F7F, 0, 0x7F7F7F7F);
      ar = __builtin_amdgcn_mfma_scale_f32_16x16x128_f8f6f4(
               wrMX[1], hB1, ar, 0, 0, 0, 0x7F7F7F7F, 0, 0x7F7F7F7F);
      az = __builtin_amdgcn_mfma_scale_f32_16x16x128_f8f6f4(
               wzMX[1], hB1, az, 0, 0, 0, 0x7F7F7F7F, 0, 0x7F7F7F7F);
    }
    float r0 = sigm(sel4(ar, lb) + uph(crx));
    float zg = sigm(sel4(az, lb) + uph(czx));
    if (owner) {
      float rh = r0 * h0;
      rh8_lds[j0] = (unsigned char)(__builtin_amdgcn_cvt_pk_fp8_f32(rh, rh, 0, false) & 0xff);
    }
    LDS_BARRIER();                                     // (1) rh ready
    // ---- Phase C: c matvec, MX fp8 K=128 (B = rh8)
    f32x4 ac = z4;
    {
      i32x8 rB0 = *(const i32x8*)(rh8_lds + khi * 32);
      i32x8 rB1 = *(const i32x8*)(rh8_lds + 128 + khi * 32);
      ac = __builtin_amdgcn_mfma_scale_f32_16x16x128_f8f6f4(
               wcMX[0], rB0, ac, 0, 0, 0, 0x7F7F7F7F, 0, 0x7F7F7F7F);
      ac = __builtin_amdgcn_mfma_scale_f32_16x16x128_f8f6f4(
               wcMX[1], rB1, ac, 0, 0, 0, 0x7F7F7F7F, 0, 0x7F7F7F7F);
    }
    float ht = tanh_fast(sel4(ac, lb) + uph(ccx));
    float hn = (1.f - zg) * h0 + zg * ht;
    h0 = hn;
    if (owner) {
      h8_lds[j0] = (unsigned char)(__builtin_amdgcn_cvt_pk_fp8_f32(hn, hn, 0, false) & 0xff);
      P[pcur + j0] = f16bits(hn);
    }
    czx = nzx; crx = nrx; ccx = ncx;
    pcur += 65536; pnext += 65536;
    LDS_BARRIER();                                     // (2) h ready
  }
  if (owner) out[(size_t)33554432 + b * 256 + j0] = h0;
}

// ---------------------------------------------------------------------------
// Kernel 3: g-gate + highway + LayerNorm as MFMA GEMM. (unchanged)
// ---------------------------------------------------------------------------
__global__ __launch_bounds__(512, 2) void g_mfma_ln(
    const float* __restrict__ Wh,
    const float* __restrict__ gamma, const float* __restrict__ beta,
    const unsigned short* __restrict__ P,
    float* __restrict__ out)
{
  __shared__ __align__(16) char As[128 * 128];    // hprev tile f16 (swizzled)
  __shared__ __align__(16) char Bs[256 * 128];    // Wg tile f16 (swizzled)
  __shared__ float red1[128][4];
  __shared__ float red2[128][4];
  __shared__ float2 murs[128];

  const int t = threadIdx.x;
  const int lane = t & 63;
  const int wid = t >> 6;
  const int wm = wid >> 2, wn = wid & 3;          // 2 x 4 wave grid
  const unsigned m0 = blockIdx.x * 128;

  float gam4[4], bet4[4];
  #pragma unroll
  for (int jq = 0; jq < 4; ++jq) {
    int col = wn * 64 + jq * 16 + (lane & 15);
    gam4[jq] = gamma[col];
    bet4[jq] = beta[col];
  }

  f32x4 acc[4][4];
  #pragma unroll
  for (int i = 0; i < 4; ++i)
    #pragma unroll
    for (int jq = 0; jq < 4; ++jq) acc[i][jq] = f32x4{0.f, 0.f, 0.f, 0.f};

  for (int kk = 0; kk < 4; ++kk) {
    __syncthreads();
    #pragma unroll
    for (int it = 0; it < 2; ++it) {
      int g = it * 512 + t;
      int row = g >> 3;
      int c8 = g & 7;
      int msrc = (int)m0 + row - 64;
      uint4 v = uint4{0u, 0u, 0u, 0u};
      if (msrc >= 0) v = *(const uint4*)(P + (unsigned)msrc * 1024 + kk * 64 + c8 * 8);
      *(uint4*)(As + row * 128 + ((c8 * 16) ^ ((row & 7) << 4))) = v;
    }
    #pragma unroll
    for (int it = 0; it < 4; ++it) {
      int g = it * 512 + t;
      int row = g >> 3;
      int c8 = g & 7;
      const float* src = Wh + row * 512 + 256 + kk * 64 + c8 * 8;
      f32x4 v0 = *(const f32x4*)(src);
      f32x4 v1 = *(const f32x4*)(src + 4);
      uint4 pw;
      pw.x = pk16(v0[0], v0[1]); pw.y = pk16(v0[2], v0[3]);
      pw.z = pk16(v1[0], v1[1]); pw.w = pk16(v1[2], v1[3]);
      *(uint4*)(Bs + row * 128 + ((c8 * 16) ^ ((row & 7) << 4))) = pw;
    }
    __syncthreads();
    #pragma unroll
    for (int k2 = 0; k2 < 2; ++k2) {
      const int kb = k2 * 64 + (lane >> 4) * 16;
      half8v a[4], bfr[4];
      #pragma unroll
      for (int i = 0; i < 4; ++i) {
        int ar = wm * 64 + i * 16 + (lane & 15);
        a[i] = *(const half8v*)(As + ar * 128 + (kb ^ ((ar & 7) << 4)));
        int br2 = wn * 64 + i * 16 + (lane & 15);
        bfr[i] = *(const half8v*)(Bs + br2 * 128 + (kb ^ ((br2 & 7) << 4)));
      }
      #pragma unroll
      for (int i = 0; i < 4; ++i)
        #pragma unroll
        for (int jq = 0; jq < 4; ++jq)
          acc[i][jq] = __builtin_amdgcn_mfma_f32_16x16x32_f16(a[i], bfr[jq], acc[i][jq], 0, 0, 0);
    }
  }

  #pragma unroll
  for (int i = 0; i < 4; ++i) {
    #pragma unroll
    for (int r = 0; r < 4; ++r) {
      unsigned mm = m0 + wm * 64 + i * 16 + ((lane >> 4) << 2) + r;
      unsigned bse = mm << 10;
      unsigned bsp = (mm - 64) << 10;
      #pragma unroll
      for (int jq = 0; jq < 4; ++jq) {
        int col2 = wn * 64 + jq * 16 + (lane & 15);
        float gx = uph(P[bse + 768 + col2]);
        float hnew = uph(P[bse + col2]);
        float hp = (mm >= 64) ? uph(P[bsp + col2]) : 0.f;
        float g = sigm(acc[i][jq][r] + gx);
        acc[i][jq][r] = g * hnew + (1.f - g) * hp;
      }
    }
  }
  #pragma unroll
  for (int i = 0; i < 4; ++i) {
    #pragma unroll
    for (int r = 0; r < 4; ++r) {
      float s1 = acc[i][0][r] + acc[i][1][r] + acc[i][2][r] + acc[i][3][r];
      float s2 = acc[i][0][r]*acc[i][0][r] + acc[i][1][r]*acc[i][1][r]
               + acc[i][2][r]*acc[i][2][r] + acc[i][3][r]*acc[i][3][r];
      s1 += __shfl_xor(s1, 1); s2 += __shfl_xor(s2, 1);
      s1 += __shfl_xor(s1, 2); s2 += __shfl_xor(s2, 2);
      s1 += __shfl_xor(s1, 4); s2 += __shfl_xor(s2, 4);
      s1 += __shfl_xor(s1, 8); s2 += __shfl_xor(s2, 8);
      if ((lane & 15) == 0) {
        int rowl = wm * 64 + i * 16 + ((lane >> 4) << 2) + r;
        red1[rowl][wn] = s1;
        red2[rowl][wn] = s2;
      }
    }
  }
  __syncthreads();
  if (t < 128) {
    float S1 = red1[t][0] + red1[t][1] + red1[t][2] + red1[t][3];
    float S2 = red2[t][0] + red2[t][1] + red2[t][2] + red2[t][3];
    float mu = S1 * (1.0f / 256.0f);
    float var = S2 * (1.0f / 256.0f) - mu * mu;
    murs[t] = make_float2(mu, rsqrtf(var + 1e-5f));
  }
  __syncthreads();
  #pragma unroll
  for (int i = 0; i < 4; ++i) {
    #pragma unroll
    for (int r = 0; r < 4; ++r) {
      int rowl = wm * 64 + i * 16 + ((lane >> 4) << 2) + r;
      float2 mr = murs[rowl];
      unsigned mm = m0 + rowl;
      #pragma unroll
      for (int jq = 0; jq < 4; ++jq) {
        int col2 = wn * 64 + jq * 16 + (lane & 15);
        out[(size_t)mm * 256 + col2] = (acc[i][jq][r] - mr.x) * mr.y * gam4[jq] + bet4[jq];
      }
    }
  }
}

extern "C" void kernel_launch(void* const* d_in, const int* in_sizes, int n_in,
                              void* d_out, int out_size, void* d_ws, size_t ws_size,
                              hipStream_t stream) {
  const float* x  = (const float*)d_in[0];
  const float* Wz = (const float*)d_in[1];
  const float* bz = (const float*)d_in[2];
  const float* Wr = (const float*)d_in[3];
  const float* br = (const float*)d_in[4];
  const float* Wc = (const float*)d_in[5];
  const float* bc = (const float*)d_in[6];
  const float* Wh = (const float*)d_in[7];
  const float* bh = (const float*)d_in[8];
  const float* gamma = (const float*)d_in[9];
  const float* beta  = (const float*)d_in[10];
  unsigned short* P = (unsigned short*)d_ws;   // 131072 x 1024 f16 = 256 MB
  float* out = (float*)d_out;

  dim3 g1(8, 1024);
  gemm_pre<<<g1, 256, 0, stream>>>(x, Wz, bz, Wr, br, Wc, bc, Wh, bh, P);
  gru_scan<<<64, 1024, 0, stream>>>(Wz, Wr, Wc, P, out);
  g_mfma_ln<<<1024, 512, 0, stream>>>(Wh, gamma, beta, P, out);
}